// Round 8
// baseline (906.847 us; speedup 1.0000x reference)
//
#include <hip/hip_runtime.h>
#include <math.h>

// SampleScoreModel fused flash kernel — fp32 in, fp32 OUT.
//
// R0-R7 forensics resolved: ALL tensors are fp32 (inputs and output). The
// 5-round absmax=471.0 plateau was my kernels writing bf16 into the fp32
// out buffer (packed bf16 pairs read back as fp32 ~= odd element + zeros).
// bf16 quantization made structurally-different kernels' outputs bit-identical
// -> identical 471.0. R3/R4 NaN = fp32 read as bf16. R0 462 = max|ref| vs 0.
// The "(bf16, ref=np)" label + uint16 branch in the traceback were pytest
// source context / hardcoded text, not evidence of output dtype.
//
// logits[b,n] = (x_b . s_n - 0.5*||s_n||^2)/denom_b (row-const -0.5||x||^2 drops)
// out = t_scale/denom * ( softmax(logits) @ samples - x ), fp32.
// QK^T: split-bf16 hi/lo 3-pass MFMA (fp32-grade d2; denom down to 1e-8 scale
// makes winner selection sensitive). s2 exact fp32 in acc init. PV: bf16 P/V.

typedef float  f32x4 __attribute__((ext_vector_type(4)));
typedef short  s16x8 __attribute__((ext_vector_type(8)));

#define LOG2E   1.44269504088896f
#define L2_10K  13.2877123795494f   /* log2(10000) */
#define L2_001 -6.64385618977472f   /* log2(0.01)  */
#define SMIN2   1e-8f               /* SIGMA_MIN^2 */
#define DDIM    256

#if defined(__has_builtin)
#if __has_builtin(__builtin_amdgcn_exp2f)
#define EXP2(x) __builtin_amdgcn_exp2f(x)
#endif
#endif
#ifndef EXP2
#define EXP2(x) exp2f(x)
#endif

__device__ __forceinline__ unsigned short bf16_rne(float f) {
  unsigned int u = __builtin_bit_cast(unsigned int, f);
  u = (u + 0x7FFFu + ((u >> 16) & 1u)) >> 16;
  return (unsigned short)u;
}
__device__ __forceinline__ float bf16_to_f(unsigned short h) {
  unsigned int u = ((unsigned int)h) << 16;
  return __builtin_bit_cast(float, u);
}
__device__ __forceinline__ float f16_to_f(unsigned short h) {
  int s = (h >> 15) & 1, e = (h >> 10) & 31, m = h & 1023;
  float v;
  if (e == 0)       v = ldexpf((float)m, -24);
  else if (e == 31) v = 3.0e38f;
  else              v = ldexpf((float)(1024 + m), e - 25);
  return s ? -v : v;
}

// t-dtype insurance (returns fp32-mode on genuine fp32 t~U[0,1)).
__device__ __forceinline__ int classify_t_dtype(const void* tp) {
  const unsigned short* u16 = (const unsigned short*)tp;
  const unsigned int*   u32 = (const unsigned int*)tp;
  int c16 = 0, c32 = 0;
  for (int i = 0; i < 128; ++i) {
    unsigned short u = u16[i];
    int e = (u >> 7) & 0xFF;
    if (!(u & 0x8000) && e >= 113 && e <= 126) c16++;
  }
  for (int i = 0; i < 64; ++i) {
    unsigned int w = u32[i];
    int e = (int)((w >> 23) & 0xFF);
    if (!(w & 0x80000000u) && e >= 113 && e <= 126) c32++;
  }
  if (c32 >= 51) return (c16 >= 102) ? 0 : 1;   // 0=bf16, 1=fp32
  return 2;                                      // 2=fp16
}
__device__ __forceinline__ float load_t(const void* tp, int i, int mode) {
  float v;
  if (mode == 0)      v = bf16_to_f(((const unsigned short*)tp)[i]);
  else if (mode == 1) v = ((const float*)tp)[i];
  else                v = f16_to_f(((const unsigned short*)tp)[i]);
  return fminf(fmaxf(v, 0.f), 1.f);   // clamp: semantically free for t in [0,1)
}

#define KSTR 264   /* 256+8 pad ushorts: 528B rows (16B-aligned) */
#define VSTR 40    /* 32+8 pad */
#define PSTR 40

struct __align__(16) Smem {
  unsigned short khi[32 * KSTR];   // K tile bf16-hi, row-major [n][d]   16896 B
  unsigned short klo[32 * KSTR];   // K tile bf16-lo                    16896 B
  unsigned short vt [256 * VSTR];  // K tile transposed [d][n], hi only 20480 B
  unsigned short p  [4][16 * PSTR];// per-wave P round-trip              5120 B
  float s2p[32][9];
  float s2h[32];
};  // ~59.25 KB

__global__ __launch_bounds__(256)
void flash_kernel(const void* __restrict__ t, const float* __restrict__ x,
                  const float* __restrict__ smp, float* __restrict__ out,
                  int B, int N)
{
  __shared__ Smem sm;
  const int tid  = threadIdx.x;
  const int wave = tid >> 6, lane = tid & 63;
  const int lq = lane >> 4, lr = lane & 15;      // quad, lane-in-quad
  const int m0 = blockIdx.x * 64 + wave * 16;    // wave owns 16 m-rows
  const int iters = N >> 5;                      // BN = 32, full N per block
  const int tmode = classify_t_dtype(t);

  // per-row (C-layout rows: lq*4 + r) softmax scale = log2e/denom
  float invd[4];
#pragma unroll
  for (int r = 0; r < 4; ++r) {
    int gm = m0 + lq * 4 + r;
    float tv = load_t(t, gm, tmode);
    float ts = EXP2(fmaf(tv, L2_10K, L2_001));
    invd[r] = LOG2E / (ts * ts + SMIN2);
  }

  // Q fragments (block-invariant): A-layout row = m0 + lr, k = ks*32 + lq*8 + j.
  // fp32 x -> split into bf16 hi + lo.
  s16x8 qhi[8], qlo[8];
  {
    const float* xr = x + (size_t)(m0 + lr) * DDIM;
#pragma unroll
    for (int ks = 0; ks < 8; ++ks) {
      const float4* p4 = (const float4*)(xr + ks * 32 + lq * 8);
      float4 a = p4[0], b = p4[1];
      float v[8] = {a.x, a.y, a.z, a.w, b.x, b.y, b.z, b.w};
#pragma unroll
      for (int j = 0; j < 8; ++j) {
        unsigned short h = bf16_rne(v[j]);
        unsigned short l = bf16_rne(v[j] - bf16_to_f(h));
        qhi[ks][j] = (short)h;
        qlo[ks][j] = (short)l;
      }
    }
  }

  f32x4 O[16];
#pragma unroll
  for (int dt = 0; dt < 16; ++dt) O[dt] = (f32x4){0.f, 0.f, 0.f, 0.f};
  float mrun[4], lrun[4];
#pragma unroll
  for (int r = 0; r < 4; ++r) { mrun[r] = -1e30f; lrun[r] = 0.f; }

  for (int it = 0; it < iters; ++it) {
    const int n0 = it * 32;
    __syncthreads();   // everyone done reading previous tile

    // ---- stage K tile: hi/lo row-major + transposed hi + exact fp32 s2 ----
    {
      const int r = tid & 31, c = tid >> 5;      // row, 32-col chunk (8 chunks)
      const float* src = smp + (size_t)(n0 + r) * DDIM + c * 32;
      float s2 = 0.f;
#pragma unroll
      for (int i = 0; i < 8; ++i) {
        float4 f = ((const float4*)src)[i];
        float v[4] = {f.x, f.y, f.z, f.w};
        unsigned short h[4], lo[4];
#pragma unroll
        for (int e = 0; e < 4; ++e) {
          h[e]  = bf16_rne(v[e]);
          lo[e] = bf16_rne(v[e] - bf16_to_f(h[e]));
          s2 = fmaf(v[e], v[e], s2);
        }
        uint2 uh, ul;
        uh.x = h[0]  | ((unsigned)h[1]  << 16); uh.y = h[2]  | ((unsigned)h[3]  << 16);
        ul.x = lo[0] | ((unsigned)lo[1] << 16); ul.y = lo[2] | ((unsigned)lo[3] << 16);
        *(uint2*)&sm.khi[r * KSTR + c * 32 + i * 4] = uh;
        *(uint2*)&sm.klo[r * KSTR + c * 32 + i * 4] = ul;
#pragma unroll
        for (int e = 0; e < 4; ++e)
          sm.vt[(c * 32 + i * 4 + e) * VSTR + r] = h[e];
      }
      sm.s2p[r][c] = s2;
    }
    __syncthreads();
    if (tid < 32) {
      float a = 0.f;
#pragma unroll
      for (int c = 0; c < 8; ++c) a += sm.s2p[tid][c];
      sm.s2h[tid] = 0.5f * a;
    }
    __syncthreads();

    // ---- QK^T (3-pass split bf16), acc init = -0.5*s2 ----
    f32x4 acc[2];
#pragma unroll
    for (int nt = 0; nt < 2; ++nt) {
      float s2v = -sm.s2h[nt * 16 + lr];
      acc[nt] = (f32x4){s2v, s2v, s2v, s2v};
    }
#pragma unroll
    for (int nt = 0; nt < 2; ++nt) {
#pragma unroll
      for (int ks = 0; ks < 8; ++ks) {
        const s16x8 bh = *(const s16x8*)&sm.khi[(nt * 16 + lr) * KSTR + ks * 32 + lq * 8];
        const s16x8 bl = *(const s16x8*)&sm.klo[(nt * 16 + lr) * KSTR + ks * 32 + lq * 8];
        acc[nt] = __builtin_amdgcn_mfma_f32_16x16x32_bf16(qhi[ks], bh, acc[nt], 0, 0, 0);
        acc[nt] = __builtin_amdgcn_mfma_f32_16x16x32_bf16(qlo[ks], bh, acc[nt], 0, 0, 0);
        acc[nt] = __builtin_amdgcn_mfma_f32_16x16x32_bf16(qhi[ks], bl, acc[nt], 0, 0, 0);
      }
    }

    // ---- online softmax (over n) + P->LDS (wave-private) + O rescale ----
#pragma unroll
    for (int r = 0; r < 4; ++r) {
      float L[2];
      L[0] = acc[0][r] * invd[r];
      L[1] = acc[1][r] * invd[r];
      float tmax = fmaxf(L[0], L[1]);
#pragma unroll
      for (int msk = 1; msk <= 8; msk <<= 1)
        tmax = fmaxf(tmax, __shfl_xor(tmax, msk));
      float mnew = fmaxf(mrun[r], tmax);
      float alpha = EXP2(mrun[r] - mnew);
      mrun[r] = mnew;
      float ps = 0.f;
#pragma unroll
      for (int nt = 0; nt < 2; ++nt) {
        unsigned short pq = bf16_rne(EXP2(L[nt] - mnew));
        ps += bf16_to_f(pq);   // sum the QUANTIZED p: consistent with PV's MFMA
        sm.p[wave][(lq * 4 + r) * PSTR + nt * 16 + lr] = pq;
      }
#pragma unroll
      for (int msk = 1; msk <= 8; msk <<= 1) ps += __shfl_xor(ps, msk);
      lrun[r] = alpha * lrun[r] + ps;
#pragma unroll
      for (int dt = 0; dt < 16; ++dt) O[dt][r] *= alpha;
    }

    // ---- PV: O += P @ V  (A from wave-private P LDS, B from transposed V) ----
    {
      const s16x8 pa = *(const s16x8*)&sm.p[wave][lr * PSTR + lq * 8];
#pragma unroll
      for (int dt = 0; dt < 16; ++dt) {
        const s16x8 bv = *(const s16x8*)&sm.vt[(dt * 16 + lr) * VSTR + lq * 8];
        O[dt] = __builtin_amdgcn_mfma_f32_16x16x32_bf16(pa, bv, O[dt], 0, 0, 0);
      }
    }
  }

  // ---- epilogue: out = ts/den * (O/l - x), fp32 ----
#pragma unroll
  for (int r = 0; r < 4; ++r) {
    int gm = m0 + lq * 4 + r;
    float tv = load_t(t, gm, tmode);
    float ts = EXP2(fmaf(tv, L2_10K, L2_001));
    float den = ts * ts + SMIN2;
    float sc = ts / den;
    float il = 1.f / lrun[r];
#pragma unroll
    for (int dt = 0; dt < 16; ++dt) {
      int d = dt * 16 + lr;
      float mean = O[dt][r] * il;
      out[(size_t)gm * DDIM + d] = sc * (mean - x[(size_t)gm * DDIM + d]);
    }
  }
}

extern "C" void kernel_launch(void* const* d_in, const int* in_sizes, int n_in,
                              void* d_out, int out_size, void* d_ws, size_t ws_size,
                              hipStream_t stream) {
  // Identify inputs BY SIZE (robust): x has out_size elements, samples is the
  // largest, t the smallest.
  int xi = 0, si = 0, ti = 0;
  for (int i = 0; i < 3; ++i) {
    if (in_sizes[i] == out_size) xi = i;
    if (in_sizes[i] > in_sizes[si]) si = i;
    if (in_sizes[i] < in_sizes[ti]) ti = i;
  }
  const void*  t   = d_in[ti];                  // fp32 [B] (runtime-classified)
  const float* x   = (const float*)d_in[xi];    // fp32 [B,256]
  const float* smp = (const float*)d_in[si];    // fp32 [N,256]
  float* out = (float*)d_out;                   // fp32 [B,256]
  int B = out_size / DDIM;          // 4096
  int N = in_sizes[si] / DDIM;      // 8192
  (void)d_ws; (void)ws_size; (void)n_in;

  flash_kernel<<<dim3(B / 64), 256, 0, stream>>>(t, x, smp, out, B, N);
}

// Round 9
// 377.174 us; speedup vs baseline: 2.4043x; 2.4043x over previous
//
#include <hip/hip_runtime.h>
#include <math.h>

// SampleScoreModel fused flash kernel — fp32 in/out. R8 passed (absmax 2.0) at
// 906 us with OccupancyPercent=3.07% (64 blocks on 256 CUs, 1 block/CU) ->
// pure parallelism bound. R9: N-split ns=8 (512 blocks, 2 blocks/CU) + combine
// kernel, and barrier #3 removed (s2 column-sum folded into acc init).
//
// logits[b,n] = (x_b . s_n - 0.5*||s_n||^2)/denom_b (row-const -0.5||x||^2 drops)
// out = t_scale/denom * ( softmax(logits) @ samples - x ), fp32.
// QK^T: split-bf16 hi/lo 3-pass MFMA. s2 exact fp32. PV: bf16 P/V.

typedef float  f32x4 __attribute__((ext_vector_type(4)));
typedef short  s16x8 __attribute__((ext_vector_type(8)));

#define LOG2E   1.44269504088896f
#define L2_10K  13.2877123795494f   /* log2(10000) */
#define L2_001 -6.64385618977472f   /* log2(0.01)  */
#define SMIN2   1e-8f               /* SIGMA_MIN^2 */
#define DDIM    256

#if defined(__has_builtin)
#if __has_builtin(__builtin_amdgcn_exp2f)
#define EXP2(x) __builtin_amdgcn_exp2f(x)
#endif
#endif
#ifndef EXP2
#define EXP2(x) exp2f(x)
#endif

__device__ __forceinline__ unsigned short bf16_rne(float f) {
  unsigned int u = __builtin_bit_cast(unsigned int, f);
  u = (u + 0x7FFFu + ((u >> 16) & 1u)) >> 16;
  return (unsigned short)u;
}
__device__ __forceinline__ float bf16_to_f(unsigned short h) {
  unsigned int u = ((unsigned int)h) << 16;
  return __builtin_bit_cast(float, u);
}
__device__ __forceinline__ float f16_to_f(unsigned short h) {
  int s = (h >> 15) & 1, e = (h >> 10) & 31, m = h & 1023;
  float v;
  if (e == 0)       v = ldexpf((float)m, -24);
  else if (e == 31) v = 3.0e38f;
  else              v = ldexpf((float)(1024 + m), e - 25);
  return s ? -v : v;
}

// t-dtype insurance (returns fp32-mode on genuine fp32 t~U[0,1)).
__device__ __forceinline__ int classify_t_dtype(const void* tp) {
  const unsigned short* u16 = (const unsigned short*)tp;
  const unsigned int*   u32 = (const unsigned int*)tp;
  int c16 = 0, c32 = 0;
  for (int i = 0; i < 128; ++i) {
    unsigned short u = u16[i];
    int e = (u >> 7) & 0xFF;
    if (!(u & 0x8000) && e >= 113 && e <= 126) c16++;
  }
  for (int i = 0; i < 64; ++i) {
    unsigned int w = u32[i];
    int e = (int)((w >> 23) & 0xFF);
    if (!(w & 0x80000000u) && e >= 113 && e <= 126) c32++;
  }
  if (c32 >= 51) return (c16 >= 102) ? 0 : 1;   // 0=bf16, 1=fp32
  return 2;                                      // 2=fp16
}
__device__ __forceinline__ float load_t(const void* tp, int i, int mode) {
  float v;
  if (mode == 0)      v = bf16_to_f(((const unsigned short*)tp)[i]);
  else if (mode == 1) v = ((const float*)tp)[i];
  else                v = f16_to_f(((const unsigned short*)tp)[i]);
  return fminf(fmaxf(v, 0.f), 1.f);
}

#define KSTR 264   /* 256+8 pad ushorts: 528B rows (16B-aligned) */
#define VSTR 40    /* 32+8 pad */
#define PSTR 40

struct __align__(16) Smem {
  unsigned short khi[32 * KSTR];   // K tile bf16-hi, row-major [n][d]   16896 B
  unsigned short klo[32 * KSTR];   // K tile bf16-lo                    16896 B
  unsigned short vt [256 * VSTR];  // K tile transposed [d][n], hi only 20480 B
  unsigned short p  [4][16 * PSTR];// per-wave P round-trip              5120 B
  float s2p[32][9];                // per-row s2 partials (8 used + pad)
};  // ~59 KB -> 2 blocks/CU

__global__ __launch_bounds__(256)
void flash_kernel(const void* __restrict__ t, const float* __restrict__ x,
                  const float* __restrict__ smp, float* __restrict__ out,
                  float* __restrict__ pO, float* __restrict__ pm,
                  float* __restrict__ pl, int B, int N)
{
  __shared__ Smem sm;
  const int tid  = threadIdx.x;
  const int wave = tid >> 6, lane = tid & 63;
  const int lq = lane >> 4, lr = lane & 15;      // quad, lane-in-quad
  const int m0 = blockIdx.x * 64 + wave * 16;    // wave owns 16 m-rows
  const int nsplit = gridDim.y, split = blockIdx.y;
  const int n_per = N / nsplit;
  const int n0b = split * n_per;
  const int iters = n_per >> 5;                  // BN = 32
  const int tmode = classify_t_dtype(t);

  float invd[4];
#pragma unroll
  for (int r = 0; r < 4; ++r) {
    int gm = m0 + lq * 4 + r;
    float tv = load_t(t, gm, tmode);
    float ts = EXP2(fmaf(tv, L2_10K, L2_001));
    invd[r] = LOG2E / (ts * ts + SMIN2);
  }

  // Q fragments (block-invariant): A-layout row = m0 + lr, k = ks*32 + lq*8 + j.
  s16x8 qhi[8], qlo[8];
  {
    const float* xr = x + (size_t)(m0 + lr) * DDIM;
#pragma unroll
    for (int ks = 0; ks < 8; ++ks) {
      const float4* p4 = (const float4*)(xr + ks * 32 + lq * 8);
      float4 a = p4[0], b = p4[1];
      float v[8] = {a.x, a.y, a.z, a.w, b.x, b.y, b.z, b.w};
#pragma unroll
      for (int j = 0; j < 8; ++j) {
        unsigned short h = bf16_rne(v[j]);
        unsigned short l = bf16_rne(v[j] - bf16_to_f(h));
        qhi[ks][j] = (short)h;
        qlo[ks][j] = (short)l;
      }
    }
  }

  f32x4 O[16];
#pragma unroll
  for (int dt = 0; dt < 16; ++dt) O[dt] = (f32x4){0.f, 0.f, 0.f, 0.f};
  float mrun[4], lrun[4];
#pragma unroll
  for (int r = 0; r < 4; ++r) { mrun[r] = -1e30f; lrun[r] = 0.f; }

  for (int it = 0; it < iters; ++it) {
    const int n0 = n0b + it * 32;
    __syncthreads();   // everyone done reading previous tile

    // ---- stage K tile: hi/lo row-major + transposed hi + exact fp32 s2 ----
    {
      const int r = tid & 31, c = tid >> 5;      // row, 32-col chunk (8 chunks)
      const float* src = smp + (size_t)(n0 + r) * DDIM + c * 32;
      float s2 = 0.f;
#pragma unroll
      for (int i = 0; i < 8; ++i) {
        float4 f = ((const float4*)src)[i];
        float v[4] = {f.x, f.y, f.z, f.w};
        unsigned short h[4], lo[4];
#pragma unroll
        for (int e = 0; e < 4; ++e) {
          h[e]  = bf16_rne(v[e]);
          lo[e] = bf16_rne(v[e] - bf16_to_f(h[e]));
          s2 = fmaf(v[e], v[e], s2);
        }
        uint2 uh, ul;
        uh.x = h[0]  | ((unsigned)h[1]  << 16); uh.y = h[2]  | ((unsigned)h[3]  << 16);
        ul.x = lo[0] | ((unsigned)lo[1] << 16); ul.y = lo[2] | ((unsigned)lo[3] << 16);
        *(uint2*)&sm.khi[r * KSTR + c * 32 + i * 4] = uh;
        *(uint2*)&sm.klo[r * KSTR + c * 32 + i * 4] = ul;
#pragma unroll
        for (int e = 0; e < 4; ++e)
          sm.vt[(c * 32 + i * 4 + e) * VSTR + r] = h[e];
      }
      sm.s2p[r][c] = s2;
    }
    __syncthreads();

    // ---- QK^T (3-pass split bf16); acc init = -0.5*sum_c s2p[row][c]
    //      (column-sum folded here: kills barrier #3 + the serial tid<32 step)
    f32x4 acc[2];
#pragma unroll
    for (int nt = 0; nt < 2; ++nt) {
      const float* sp = sm.s2p[nt * 16 + lr];
      float4 a = *(const float4*)sp, b = *(const float4*)(sp + 4);
      float s2v = -0.5f * ((a.x + a.y) + (a.z + a.w) + ((b.x + b.y) + (b.z + b.w)));
      acc[nt] = (f32x4){s2v, s2v, s2v, s2v};
    }
#pragma unroll
    for (int nt = 0; nt < 2; ++nt) {
#pragma unroll
      for (int ks = 0; ks < 8; ++ks) {
        const s16x8 bh = *(const s16x8*)&sm.khi[(nt * 16 + lr) * KSTR + ks * 32 + lq * 8];
        const s16x8 bl = *(const s16x8*)&sm.klo[(nt * 16 + lr) * KSTR + ks * 32 + lq * 8];
        acc[nt] = __builtin_amdgcn_mfma_f32_16x16x32_bf16(qhi[ks], bh, acc[nt], 0, 0, 0);
        acc[nt] = __builtin_amdgcn_mfma_f32_16x16x32_bf16(qlo[ks], bh, acc[nt], 0, 0, 0);
        acc[nt] = __builtin_amdgcn_mfma_f32_16x16x32_bf16(qhi[ks], bl, acc[nt], 0, 0, 0);
      }
    }

    // ---- online softmax (over n) + P->LDS (wave-private) + O rescale ----
#pragma unroll
    for (int r = 0; r < 4; ++r) {
      float L[2];
      L[0] = acc[0][r] * invd[r];
      L[1] = acc[1][r] * invd[r];
      float tmax = fmaxf(L[0], L[1]);
#pragma unroll
      for (int msk = 1; msk <= 8; msk <<= 1)
        tmax = fmaxf(tmax, __shfl_xor(tmax, msk));
      float mnew = fmaxf(mrun[r], tmax);
      float alpha = EXP2(mrun[r] - mnew);
      mrun[r] = mnew;
      float ps = 0.f;
#pragma unroll
      for (int nt = 0; nt < 2; ++nt) {
        unsigned short pq = bf16_rne(EXP2(L[nt] - mnew));
        ps += bf16_to_f(pq);   // sum the QUANTIZED p: consistent with PV
        sm.p[wave][(lq * 4 + r) * PSTR + nt * 16 + lr] = pq;
      }
#pragma unroll
      for (int msk = 1; msk <= 8; msk <<= 1) ps += __shfl_xor(ps, msk);
      lrun[r] = alpha * lrun[r] + ps;
#pragma unroll
      for (int dt = 0; dt < 16; ++dt) O[dt][r] *= alpha;
    }

    // ---- PV: O += P @ V ----
    {
      const s16x8 pa = *(const s16x8*)&sm.p[wave][lr * PSTR + lq * 8];
#pragma unroll
      for (int dt = 0; dt < 16; ++dt) {
        const s16x8 bv = *(const s16x8*)&sm.vt[(dt * 16 + lr) * VSTR + lq * 8];
        O[dt] = __builtin_amdgcn_mfma_f32_16x16x32_bf16(pa, bv, O[dt], 0, 0, 0);
      }
    }
  }

  // ---- epilogue ----
  if (nsplit == 1) {
#pragma unroll
    for (int r = 0; r < 4; ++r) {
      int gm = m0 + lq * 4 + r;
      float tv = load_t(t, gm, tmode);
      float ts = EXP2(fmaf(tv, L2_10K, L2_001));
      float den = ts * ts + SMIN2;
      float sc = ts / den;
      float il = 1.f / lrun[r];
#pragma unroll
      for (int dt = 0; dt < 16; ++dt) {
        int d = dt * 16 + lr;
        out[(size_t)gm * DDIM + d] = sc * (O[dt][r] * il - x[(size_t)gm * DDIM + d]);
      }
    }
  } else {
    size_t obase = (size_t)split * B * DDIM;
#pragma unroll
    for (int r = 0; r < 4; ++r) {
      int gm = m0 + lq * 4 + r;
#pragma unroll
      for (int dt = 0; dt < 16; ++dt)
        pO[obase + (size_t)gm * DDIM + dt * 16 + lr] = O[dt][r];
      if (lr == 0) {
        pm[(size_t)split * B + gm] = mrun[r];
        pl[(size_t)split * B + gm] = lrun[r];
      }
    }
  }
}

__global__ __launch_bounds__(256)
void combine_kernel(const void* __restrict__ t, const float* __restrict__ x,
                    const float* __restrict__ pO, const float* __restrict__ pm,
                    const float* __restrict__ pl, float* __restrict__ out,
                    int nsplit, int B)
{
  int idx = blockIdx.x * 256 + threadIdx.x;   // over B*256
  int b = idx >> 8;
  const int tmode = classify_t_dtype(t);
  float M = -1e30f;
  for (int s = 0; s < nsplit; ++s) M = fmaxf(M, pm[(size_t)s * B + b]);
  float num = 0.f, den = 0.f;
  for (int s = 0; s < nsplit; ++s) {
    float w = EXP2(pm[(size_t)s * B + b] - M);
    num += w * pO[(size_t)s * B * DDIM + idx];
    den += w * pl[(size_t)s * B + b];
  }
  float mean = num / den;
  float tv = load_t(t, b, tmode);
  float ts = EXP2(fmaf(tv, L2_10K, L2_001));
  float dd = ts * ts + SMIN2;
  out[idx] = ts * (mean - x[idx]) / dd;
}

extern "C" void kernel_launch(void* const* d_in, const int* in_sizes, int n_in,
                              void* d_out, int out_size, void* d_ws, size_t ws_size,
                              hipStream_t stream) {
  // Identify inputs BY SIZE: x has out_size elements, samples largest, t smallest.
  int xi = 0, si = 0, ti = 0;
  for (int i = 0; i < 3; ++i) {
    if (in_sizes[i] == out_size) xi = i;
    if (in_sizes[i] > in_sizes[si]) si = i;
    if (in_sizes[i] < in_sizes[ti]) ti = i;
  }
  const void*  t   = d_in[ti];                  // fp32 [B]
  const float* x   = (const float*)d_in[xi];    // fp32 [B,256]
  const float* smp = (const float*)d_in[si];    // fp32 [N,256]
  float* out = (float*)d_out;                   // fp32 [B,256]
  int B = out_size / DDIM;          // 4096
  int N = in_sizes[si] / DDIM;      // 8192

  // N-split from workspace capacity (ws_size fixed across calls -> deterministic)
  size_t per = (size_t)B * DDIM * sizeof(float) + (size_t)B * 2 * sizeof(float);
  int ns = 8;
  while (ns > 1 && (size_t)ns * per > ws_size) ns >>= 1;

  float* pO = (float*)d_ws;
  float* pm = pO + (size_t)ns * B * DDIM;
  float* pl = pm + (size_t)ns * B;

  dim3 grid(B / 64, ns);
  flash_kernel<<<grid, 256, 0, stream>>>(t, x, smp, out, pO, pm, pl, B, N);
  if (ns > 1)
    combine_kernel<<<(B * DDIM) / 256, 256, 0, stream>>>(t, x, pO, pm, pl, out, ns, B);
}

// Round 10
// 213.121 us; speedup vs baseline: 4.2551x; 1.7698x over previous
//
#include <hip/hip_runtime.h>
#include <math.h>

// SampleScoreModel fused flash kernel — fp32 in/out.
// R9: 377us, flash 292us; staging dominates (200 VALU convert insts dependent on
// global loads + 32 scalar ds_write_b16 transpose -> 1.7e7 bank-conflict cycles).
// R10: one-time precompute kernels build bf16 hi/lo planes (gkhi/gklo), a
// tile-blocked pre-transposed V (gvt, coalesced reads), and 0.5*||s||^2 (gs2).
// Flash stages via 12x16B coalesced loads + swizzled ds_write_b128, with a
// register-prefetch pipeline (tile k+1 loads in flight during tile k compute).
// Combine vectorized float4.

typedef float  f32x4 __attribute__((ext_vector_type(4)));
typedef short  s16x8 __attribute__((ext_vector_type(8)));
typedef unsigned short u16;

#define LOG2E   1.44269504088896f
#define L2_10K  13.2877123795494f   /* log2(10000) */
#define L2_001 -6.64385618977472f   /* log2(0.01)  */
#define SMIN2   1e-8f               /* SIGMA_MIN^2 */
#define DDIM    256

#if defined(__has_builtin)
#if __has_builtin(__builtin_amdgcn_exp2f)
#define EXP2(x) __builtin_amdgcn_exp2f(x)
#endif
#endif
#ifndef EXP2
#define EXP2(x) exp2f(x)
#endif

__device__ __forceinline__ u16 bf16_rne(float f) {
  unsigned int u = __builtin_bit_cast(unsigned int, f);
  u = (u + 0x7FFFu + ((u >> 16) & 1u)) >> 16;
  return (u16)u;
}
__device__ __forceinline__ float bf16_to_f(u16 h) {
  unsigned int u = ((unsigned int)h) << 16;
  return __builtin_bit_cast(float, u);
}
__device__ __forceinline__ float f16_to_f(u16 h) {
  int s = (h >> 15) & 1, e = (h >> 10) & 31, m = h & 1023;
  float v;
  if (e == 0)       v = ldexpf((float)m, -24);
  else if (e == 31) v = 3.0e38f;
  else              v = ldexpf((float)(1024 + m), e - 25);
  return s ? -v : v;
}

// t-dtype insurance (returns fp32-mode on genuine fp32 t~U[0,1)).
__device__ __forceinline__ int classify_t_dtype(const void* tp) {
  const u16*          u16p = (const u16*)tp;
  const unsigned int* u32p = (const unsigned int*)tp;
  int c16 = 0, c32 = 0;
  for (int i = 0; i < 128; ++i) {
    u16 u = u16p[i];
    int e = (u >> 7) & 0xFF;
    if (!(u & 0x8000) && e >= 113 && e <= 126) c16++;
  }
  for (int i = 0; i < 64; ++i) {
    unsigned int w = u32p[i];
    int e = (int)((w >> 23) & 0xFF);
    if (!(w & 0x80000000u) && e >= 113 && e <= 126) c32++;
  }
  if (c32 >= 51) return (c16 >= 102) ? 0 : 1;   // 0=bf16, 1=fp32
  return 2;                                      // 2=fp16
}
__device__ __forceinline__ float load_t(const void* tp, int i, int mode) {
  float v;
  if (mode == 0)      v = bf16_to_f(((const u16*)tp)[i]);
  else if (mode == 1) v = ((const float*)tp)[i];
  else                v = f16_to_f(((const u16*)tp)[i]);
  return fminf(fmaxf(v, 0.f), 1.f);
}

// ---------------- precompute kernels ----------------

// Row-major bf16 hi/lo planes + 0.5*||s||^2. Wave per row; lane owns 4 elems.
__global__ __launch_bounds__(256)
void prep_rows(const float* __restrict__ smp, u16* __restrict__ gkhi,
               u16* __restrict__ gklo, float* __restrict__ gs2, int N)
{
  int row  = blockIdx.x * 4 + (threadIdx.x >> 6);
  int lane = threadIdx.x & 63;
  float4 v4 = *(const float4*)(smp + (size_t)row * DDIM + lane * 4);
  float v[4] = {v4.x, v4.y, v4.z, v4.w};
  ushort4 h, l;
  u16 hh[4], ll[4];
  float s2 = 0.f;
#pragma unroll
  for (int e = 0; e < 4; ++e) {
    hh[e] = bf16_rne(v[e]);
    ll[e] = bf16_rne(v[e] - bf16_to_f(hh[e]));
    s2 = fmaf(v[e], v[e], s2);
  }
  h.x = hh[0]; h.y = hh[1]; h.z = hh[2]; h.w = hh[3];
  l.x = ll[0]; l.y = ll[1]; l.z = ll[2]; l.w = ll[3];
  *(ushort4*)(gkhi + (size_t)row * DDIM + lane * 4) = h;
  *(ushort4*)(gklo + (size_t)row * DDIM + lane * 4) = l;
#pragma unroll
  for (int msk = 1; msk <= 32; msk <<= 1) s2 += __shfl_xor(s2, msk);
  if (lane == 0) gs2[row] = 0.5f * s2;
}

// Tile-blocked transposed V (bf16 hi): gvt[(n0/32)*256 + d][0..31] = V[n0+nn][d]
// -> flash reads per-tile 16 KB fully contiguous & coalesced.
__global__ __launch_bounds__(256)
void prep_t(const float* __restrict__ smp, u16* __restrict__ gvt, int N)
{
  int d  = threadIdx.x;
  int n0 = blockIdx.x * 32;
  u16 buf[32];
#pragma unroll
  for (int i = 0; i < 32; ++i)
    buf[i] = bf16_rne(smp[(size_t)(n0 + i) * DDIM + d]);   // coalesced across threads
  u16* dst = gvt + ((size_t)blockIdx.x * 256 + d) * 32;
#pragma unroll
  for (int j = 0; j < 4; ++j)
    *(s16x8*)(dst + j * 8) = *(s16x8*)&buf[j * 8];
}

// ---------------- flash kernel ----------------

#define KSTR 264   /* 256+8 pad ushorts: 528B rows (verified-ladder pattern) */
#define VSTR 40    /* 32+8: 80B rows, 16B-aligned chunks; chunk XOR-swizzled */
#define PSTR 40

struct __align__(16) Smem {
  u16 khi[32 * KSTR];    // 16896 B  K tile bf16-hi, row-major [n][d]
  u16 klo[32 * KSTR];    // 16896 B  K tile bf16-lo
  u16 vt [256 * VSTR];   // 20480 B  V^T tile [d][n], 16B chunks swizzled
  u16 p  [4][16 * PSTR]; //  5120 B  per-wave P round-trip
};  // 59392 B -> 2 blocks/CU

__global__ __launch_bounds__(256, 2)
void flash_kernel(const void* __restrict__ t, const float* __restrict__ x,
                  const u16* __restrict__ gkhi, const u16* __restrict__ gklo,
                  const u16* __restrict__ gvt, const float* __restrict__ gs2,
                  float* __restrict__ out,
                  float* __restrict__ pO, float* __restrict__ pm,
                  float* __restrict__ pl, int B, int N)
{
  __shared__ Smem sm;
  const int tid  = threadIdx.x;
  const int wave = tid >> 6, lane = tid & 63;
  const int lq = lane >> 4, lr = lane & 15;      // quad, lane-in-quad
  const int m0 = blockIdx.x * 64 + wave * 16;    // wave owns 16 m-rows
  const int nsplit = gridDim.y, split = blockIdx.y;
  const int n_per = N / nsplit;
  const int n0b = split * n_per;
  const int iters = n_per >> 5;                  // BN = 32
  const int tmode = classify_t_dtype(t);

  float invd[4];
#pragma unroll
  for (int r = 0; r < 4; ++r) {
    int gm = m0 + lq * 4 + r;
    float tv = load_t(t, gm, tmode);
    float ts = EXP2(fmaf(tv, L2_10K, L2_001));
    invd[r] = LOG2E / (ts * ts + SMIN2);
  }

  // Q fragments (block-invariant): A-layout row = m0 + lr, k = ks*32 + lq*8 + j.
  s16x8 qhi[8], qlo[8];
  {
    const float* xr = x + (size_t)(m0 + lr) * DDIM;
#pragma unroll
    for (int ks = 0; ks < 8; ++ks) {
      const float4* p4 = (const float4*)(xr + ks * 32 + lq * 8);
      float4 a = p4[0], b = p4[1];
      float v[8] = {a.x, a.y, a.z, a.w, b.x, b.y, b.z, b.w};
#pragma unroll
      for (int j = 0; j < 8; ++j) {
        u16 h = bf16_rne(v[j]);
        u16 l = bf16_rne(v[j] - bf16_to_f(h));
        qhi[ks][j] = (short)h;
        qlo[ks][j] = (short)l;
      }
    }
  }

  f32x4 O[16];
#pragma unroll
  for (int dt = 0; dt < 16; ++dt) O[dt] = (f32x4){0.f, 0.f, 0.f, 0.f};
  float mrun[4], lrun[4];
#pragma unroll
  for (int r = 0; r < 4; ++r) { mrun[r] = -1e30f; lrun[r] = 0.f; }

  // staging indices (fixed per thread)
  const int sr = tid & 31, scc = tid >> 5;       // khi/klo: row, 32-col chunk
  const int vsw = (tid >> 3) & 3;                // vt chunk swizzle key

  // prefetch registers: 4x khi, 4x klo, 4x vt (16B each)
  s16x8 pk[4], plr[4], pv[4];
  float s2a, s2b;

  {  // issue tile 0
    const s16x8* kb = (const s16x8*)(gkhi + (size_t)(n0b + sr) * DDIM + scc * 32);
    const s16x8* lb = (const s16x8*)(gklo + (size_t)(n0b + sr) * DDIM + scc * 32);
    const s16x8* vb = (const s16x8*)(gvt + ((size_t)(n0b >> 5) * 256 + tid) * 32);
#pragma unroll
    for (int j = 0; j < 4; ++j) { pk[j] = kb[j]; plr[j] = lb[j]; pv[j] = vb[j]; }
    s2a = gs2[n0b + lr]; s2b = gs2[n0b + 16 + lr];
  }

  int n0 = n0b;
  for (int it = 0; it < iters; ++it) {
    __syncthreads();   // previous tile fully consumed

    // ---- commit prefetched tile to LDS (vector writes; vt swizzled) ----
#pragma unroll
    for (int j = 0; j < 4; ++j) {
      *(s16x8*)&sm.khi[sr * KSTR + scc * 32 + j * 8] = pk[j];
      *(s16x8*)&sm.klo[sr * KSTR + scc * 32 + j * 8] = plr[j];
      *(s16x8*)&sm.vt[tid * VSTR + 8 * (j ^ vsw)]    = pv[j];
    }
    float cs2a = s2a, cs2b = s2b;
    __syncthreads();

    // ---- kick prefetch for next tile (drains during compute below) ----
    if (it + 1 < iters) {
      int nn = n0 + 32;
      const s16x8* kb = (const s16x8*)(gkhi + (size_t)(nn + sr) * DDIM + scc * 32);
      const s16x8* lb = (const s16x8*)(gklo + (size_t)(nn + sr) * DDIM + scc * 32);
      const s16x8* vb = (const s16x8*)(gvt + ((size_t)(nn >> 5) * 256 + tid) * 32);
#pragma unroll
      for (int j = 0; j < 4; ++j) { pk[j] = kb[j]; plr[j] = lb[j]; pv[j] = vb[j]; }
      s2a = gs2[nn + lr]; s2b = gs2[nn + 16 + lr];
    }

    // ---- QK^T (3-pass split bf16); acc init = -0.5*||s||^2 (from gs2) ----
    f32x4 acc[2];
    acc[0] = (f32x4){-cs2a, -cs2a, -cs2a, -cs2a};
    acc[1] = (f32x4){-cs2b, -cs2b, -cs2b, -cs2b};
#pragma unroll
    for (int nt = 0; nt < 2; ++nt) {
#pragma unroll
      for (int ks = 0; ks < 8; ++ks) {
        const s16x8 bh = *(const s16x8*)&sm.khi[(nt * 16 + lr) * KSTR + ks * 32 + lq * 8];
        const s16x8 bl = *(const s16x8*)&sm.klo[(nt * 16 + lr) * KSTR + ks * 32 + lq * 8];
        acc[nt] = __builtin_amdgcn_mfma_f32_16x16x32_bf16(qhi[ks], bh, acc[nt], 0, 0, 0);
        acc[nt] = __builtin_amdgcn_mfma_f32_16x16x32_bf16(qlo[ks], bh, acc[nt], 0, 0, 0);
        acc[nt] = __builtin_amdgcn_mfma_f32_16x16x32_bf16(qhi[ks], bl, acc[nt], 0, 0, 0);
      }
    }

    // ---- online softmax + P->LDS (wave-private) + O rescale ----
#pragma unroll
    for (int r = 0; r < 4; ++r) {
      float L[2];
      L[0] = acc[0][r] * invd[r];
      L[1] = acc[1][r] * invd[r];
      float tmax = fmaxf(L[0], L[1]);
#pragma unroll
      for (int msk = 1; msk <= 8; msk <<= 1)
        tmax = fmaxf(tmax, __shfl_xor(tmax, msk));
      float mnew = fmaxf(mrun[r], tmax);
      float alpha = EXP2(mrun[r] - mnew);
      mrun[r] = mnew;
      float ps = 0.f;
#pragma unroll
      for (int nt = 0; nt < 2; ++nt) {
        u16 pq = bf16_rne(EXP2(L[nt] - mnew));
        ps += bf16_to_f(pq);   // sum the QUANTIZED p: consistent with PV
        sm.p[wave][(lq * 4 + r) * PSTR + nt * 16 + lr] = pq;
      }
#pragma unroll
      for (int msk = 1; msk <= 8; msk <<= 1) ps += __shfl_xor(ps, msk);
      lrun[r] = alpha * lrun[r] + ps;
#pragma unroll
      for (int dt = 0; dt < 16; ++dt) O[dt][r] *= alpha;
    }

    // ---- PV: O += P @ V  (vt read undoes the chunk swizzle) ----
    {
      const s16x8 pa = *(const s16x8*)&sm.p[wave][lr * PSTR + lq * 8];
#pragma unroll
      for (int dt = 0; dt < 16; ++dt) {
        int row = dt * 16 + lr;
        const s16x8 bv = *(const s16x8*)&sm.vt[row * VSTR + 8 * (lq ^ ((row >> 3) & 3))];
        O[dt] = __builtin_amdgcn_mfma_f32_16x16x32_bf16(pa, bv, O[dt], 0, 0, 0);
      }
    }
    n0 += 32;
  }

  // ---- epilogue ----
  if (nsplit == 1) {
#pragma unroll
    for (int r = 0; r < 4; ++r) {
      int gm = m0 + lq * 4 + r;
      float tv = load_t(t, gm, tmode);
      float ts = EXP2(fmaf(tv, L2_10K, L2_001));
      float den = ts * ts + SMIN2;
      float sc = ts / den;
      float il = 1.f / lrun[r];
#pragma unroll
      for (int dt = 0; dt < 16; ++dt) {
        int d = dt * 16 + lr;
        out[(size_t)gm * DDIM + d] = sc * (O[dt][r] * il - x[(size_t)gm * DDIM + d]);
      }
    }
  } else {
    size_t obase = (size_t)split * B * DDIM;
#pragma unroll
    for (int r = 0; r < 4; ++r) {
      int gm = m0 + lq * 4 + r;
#pragma unroll
      for (int dt = 0; dt < 16; ++dt)
        pO[obase + (size_t)gm * DDIM + dt * 16 + lr] = O[dt][r];
      if (lr == 0) {
        pm[(size_t)split * B + gm] = mrun[r];
        pl[(size_t)split * B + gm] = lrun[r];
      }
    }
  }
}

// ---------------- combine (float4) ----------------
__global__ __launch_bounds__(256)
void combine_kernel(const void* __restrict__ t, const float* __restrict__ x,
                    const float* __restrict__ pO, const float* __restrict__ pm,
                    const float* __restrict__ pl, float* __restrict__ out,
                    int nsplit, int B)
{
  int idx = blockIdx.x * 256 + threadIdx.x;   // over B*64 float4s
  int b = idx >> 6;
  const int tmode = classify_t_dtype(t);
  float M = -1e30f;
  for (int s = 0; s < nsplit; ++s) M = fmaxf(M, pm[(size_t)s * B + b]);
  float4 num = {0.f, 0.f, 0.f, 0.f};
  float den = 0.f;
  for (int s = 0; s < nsplit; ++s) {
    float w = EXP2(pm[(size_t)s * B + b] - M);
    float4 po = ((const float4*)pO)[(size_t)s * B * 64 + idx];
    num.x += w * po.x; num.y += w * po.y; num.z += w * po.z; num.w += w * po.w;
    den += w * pl[(size_t)s * B + b];
  }
  float il = 1.f / den;
  float tv = load_t(t, b, tmode);
  float ts = EXP2(fmaf(tv, L2_10K, L2_001));
  float sc = ts / (ts * ts + SMIN2);
  float4 xx = ((const float4*)x)[idx];
  float4 o;
  o.x = sc * (num.x * il - xx.x);
  o.y = sc * (num.y * il - xx.y);
  o.z = sc * (num.z * il - xx.z);
  o.w = sc * (num.w * il - xx.w);
  ((float4*)out)[idx] = o;
}

extern "C" void kernel_launch(void* const* d_in, const int* in_sizes, int n_in,
                              void* d_out, int out_size, void* d_ws, size_t ws_size,
                              hipStream_t stream) {
  // Identify inputs BY SIZE: x has out_size elements, samples largest, t smallest.
  int xi = 0, si = 0, ti = 0;
  for (int i = 0; i < 3; ++i) {
    if (in_sizes[i] == out_size) xi = i;
    if (in_sizes[i] > in_sizes[si]) si = i;
    if (in_sizes[i] < in_sizes[ti]) ti = i;
  }
  const void*  t   = d_in[ti];                  // fp32 [B]
  const float* x   = (const float*)d_in[xi];    // fp32 [B,256]
  const float* smp = (const float*)d_in[si];    // fp32 [N,256]
  float* out = (float*)d_out;                   // fp32 [B,256]
  int B = out_size / DDIM;          // 4096
  int N = in_sizes[si] / DDIM;      // 8192

  // ws layout: gkhi | gklo | gvt | gs2 | pO | pm | pl
  size_t plane = (size_t)N * DDIM;              // elements per u16 plane
  u16*   gkhi = (u16*)d_ws;
  u16*   gklo = gkhi + plane;
  u16*   gvt  = gklo + plane;
  float* gs2  = (float*)(gvt + plane);
  float* pO   = gs2 + N;
  size_t fixed = plane * 6 + (size_t)N * 4;     // bytes
  size_t per = (size_t)B * DDIM * sizeof(float) + (size_t)B * 2 * sizeof(float);
  int ns = 8;
  while (ns > 1 && fixed + (size_t)ns * per > ws_size) ns >>= 1;
  float* pm = pO + (size_t)ns * B * 64 * 4;
  float* pl = pm + (size_t)ns * B;

  prep_rows<<<dim3(N / 4), 256, 0, stream>>>(smp, gkhi, gklo, gs2, N);
  prep_t<<<dim3(N / 32), 256, 0, stream>>>(smp, gvt, N);
  flash_kernel<<<dim3(B / 64, ns), 256, 0, stream>>>(t, x, gkhi, gklo, gvt, gs2,
                                                     out, pO, pm, pl, B, N);
  if (ns > 1)
    combine_kernel<<<dim3(B * 64 / 256), 256, 0, stream>>>(t, x, pO, pm, pl, out, ns, B);
}